// Round 11
// baseline (418.434 us; speedup 1.0000x reference)
//
#include <hip/hip_runtime.h>

#define NN 100000
#define NE 1600000
#define WIN 12500

typedef __bf16 bf16x8 __attribute__((ext_vector_type(8)));
typedef float f32x4 __attribute__((ext_vector_type(4)));
typedef float f32x2 __attribute__((ext_vector_type(2)));

static __device__ __forceinline__ unsigned short f2bf(float f) {
  unsigned int u = __float_as_uint(f);
  unsigned int r = (u + 0x7fff + ((u >> 16) & 1)) >> 16;  // RNE
  return (unsigned short)r;
}
static __device__ __forceinline__ f32x2 unpk(unsigned int u) {
  f32x2 r;
  r.x = __uint_as_float(u << 16);
  r.y = __uint_as_float(u & 0xffff0000u);
  return r;
}

// ---------------- src-degree histogram (atomic coalesced merge) ----------------
__global__ __launch_bounds__(256) void histsrc_kernel(
    const int* __restrict__ src, int* __restrict__ degO) {
  __shared__ int hist[WIN];
  const int win = blockIdx.x & 7;
  const int chunk = blockIdx.x >> 3;  // 0..31
  const int w0 = win * WIN;
  const int w1 = w0 + WIN;
  for (int i = threadIdx.x; i < WIN; i += 256) hist[i] = 0;
  __syncthreads();
  const int per = NE / 32;
  const int e0 = chunk * per;
  const int e1 = e0 + per;
  for (int e = e0 + threadIdx.x * 4; e + 3 < e1; e += 256 * 4) {
    int4 v = *reinterpret_cast<const int4*>(src + e);
    if (v.x >= w0 && v.x < w1) atomicAdd(&hist[v.x - w0], 1);
    if (v.y >= w0 && v.y < w1) atomicAdd(&hist[v.y - w0], 1);
    if (v.z >= w0 && v.z < w1) atomicAdd(&hist[v.z - w0], 1);
    if (v.w >= w0 && v.w < w1) atomicAdd(&hist[v.w - w0], 1);
  }
  __syncthreads();
  for (int i = threadIdx.x; i < WIN; i += 256) {
    int c = hist[i];
    if (c) atomicAdd(&degO[w0 + i], c);
  }
}

// ---------------- dst histogram with per-chunk plain stores ----------------
__global__ __launch_bounds__(256) void histdst_kernel(
    const int* __restrict__ dst, int* __restrict__ C) {
  __shared__ int hist[WIN];
  const int win = blockIdx.x & 7;
  const int chunk = blockIdx.x >> 3;  // 0..31
  const int w0 = win * WIN;
  const int w1 = w0 + WIN;
  for (int i = threadIdx.x; i < WIN; i += 256) hist[i] = 0;
  __syncthreads();
  const int per = NE / 32;  // 50000
  const int e0 = chunk * per;
  const int e1 = e0 + per;
  for (int e = e0 + threadIdx.x * 4; e + 3 < e1; e += 256 * 4) {
    int4 v = *reinterpret_cast<const int4*>(dst + e);
    if (v.x >= w0 && v.x < w1) atomicAdd(&hist[v.x - w0], 1);
    if (v.y >= w0 && v.y < w1) atomicAdd(&hist[v.y - w0], 1);
    if (v.z >= w0 && v.z < w1) atomicAdd(&hist[v.z - w0], 1);
    if (v.w >= w0 && v.w < w1) atomicAdd(&hist[v.w - w0], 1);
  }
  __syncthreads();
  for (int i = threadIdx.x; i < WIN; i += 256)
    C[(size_t)chunk * NN + w0 + i] = hist[i];
}

// ---------------- chunk-scan + true degI + padded deg + fused norms ----------------
__global__ __launch_bounds__(256) void chunkscan_kernel(
    int* __restrict__ C, const int* __restrict__ degO,
    int* __restrict__ degI, int* __restrict__ dpad,
    float* __restrict__ ns, float* __restrict__ nd) {
  int n = blockIdx.x * blockDim.x + threadIdx.x;
  if (n >= NN) return;
  int acc = 0;
#pragma unroll
  for (int c = 0; c < 32; ++c) {
    int t = C[(size_t)c * NN + n];
    C[(size_t)c * NN + n] = acc;
    acc += t;
  }
  degI[n] = acc;
  dpad[n] = (acc + 7) & ~7;
  nd[n] = rsqrtf(fmaxf((float)acc, 1.0f));
  ns[n] = rsqrtf(fmaxf((float)degO[n], 1.0f));
  if (n == 0) dpad[NN] = 0;
}

// ---------------- prefix scan (over NN+1 entries of dpad) ----------------
__global__ __launch_bounds__(1024) void scan1_kernel(
    const int* __restrict__ deg, int* __restrict__ excl,
    int* __restrict__ blk, int n) {
  __shared__ int lds[1024];
  const int tid = threadIdx.x;
  const int gid = blockIdx.x * 1024 + tid;
  int v = (gid < n) ? deg[gid] : 0;
  lds[tid] = v;
  __syncthreads();
  for (int off = 1; off < 1024; off <<= 1) {
    int t = (tid >= off) ? lds[tid - off] : 0;
    __syncthreads();
    lds[tid] += t;
    __syncthreads();
  }
  if (gid < n) excl[gid] = lds[tid] - v;
  if (tid == 1023) blk[blockIdx.x] = lds[1023];
}

__global__ __launch_bounds__(128) void scan2_kernel(int* __restrict__ blk, int nblk) {
  __shared__ int lds[128];
  const int tid = threadIdx.x;
  int v = (tid < nblk) ? blk[tid] : 0;
  lds[tid] = v;
  __syncthreads();
  for (int off = 1; off < 128; off <<= 1) {
    int t = (tid >= off) ? lds[tid - off] : 0;
    __syncthreads();
    lds[tid] += t;
    __syncthreads();
  }
  if (tid < nblk) blk[tid] = lds[tid] - v;
}

__global__ __launch_bounds__(1024) void scan3_kernel(
    int* __restrict__ row_off, const int* __restrict__ blk, int n) {
  int gid = blockIdx.x * 1024 + threadIdx.x;
  if (gid < n) row_off[gid] += blk[gid >> 10];
}

// ---------------- pad filler: dummy edges -> zero row NN ----------------
__global__ __launch_bounds__(256) void padfill_kernel(
    const int* __restrict__ row_off, const int* __restrict__ degI,
    int* __restrict__ col) {
  int n = blockIdx.x * blockDim.x + threadIdx.x;
  if (n >= NN) return;
  int e = row_off[n] + degI[n];
  int e1 = row_off[n + 1];
  for (; e < e1; ++e) col[e] = NN;
}

// ---------------- scatter via LDS cursors (no global atomics) ----------------
__global__ __launch_bounds__(256) void scatter2_kernel(
    const int* __restrict__ src, const int* __restrict__ dst,
    const int* __restrict__ row_off, const int* __restrict__ C,
    int* __restrict__ col) {
  __shared__ int cur[WIN];
  const int win = blockIdx.x & 7;
  const int chunk = blockIdx.x >> 3;  // 0..31
  const int w0 = win * WIN;
  const int w1 = w0 + WIN;
  for (int i = threadIdx.x; i < WIN; i += 256)
    cur[i] = row_off[w0 + i] + C[(size_t)chunk * NN + w0 + i];
  __syncthreads();
  const int per = NE / 32;
  const int e0 = chunk * per;
  const int e1 = e0 + per;
  for (int e = e0 + threadIdx.x * 4; e + 3 < e1; e += 256 * 4) {
    int4 d4 = *reinterpret_cast<const int4*>(dst + e);
    int4 s4 = *reinterpret_cast<const int4*>(src + e);
    if (d4.x >= w0 && d4.x < w1) col[atomicAdd(&cur[d4.x - w0], 1)] = s4.x;
    if (d4.y >= w0 && d4.y < w1) col[atomicAdd(&cur[d4.y - w0], 1)] = s4.y;
    if (d4.z >= w0 && d4.z < w1) col[atomicAdd(&cur[d4.z - w0], 1)] = s4.z;
    if (d4.w >= w0 && d4.w < w1) col[atomicAdd(&cur[d4.w - w0], 1)] = s4.w;
  }
}

// ---------------- all weights transpose+convert in one launch ----------------
__global__ __launch_bounds__(256) void wconv_all_kernel(
    const float* __restrict__ W1, unsigned short* __restrict__ Wt1,
    const float* __restrict__ W2, unsigned short* __restrict__ Wt2,
    const float* __restrict__ W3, unsigned short* __restrict__ Wt3,
    const float* __restrict__ W4, unsigned short* __restrict__ Wt4) {
  int gid = blockIdx.x * blockDim.x + threadIdx.x;
  const float* W;
  unsigned short* Wt;
  int K, C, i;
  if (gid < 16384) { W = W1; Wt = Wt1; K = 128; C = 128; i = gid; }
  else if (gid < 32768) { W = W2; Wt = Wt2; K = 128; C = 128; i = gid - 16384; }
  else if (gid < 65536) { W = W3; Wt = Wt3; K = 128; C = 256; i = gid - 32768; }
  else if (gid < 81920) { W = W4; Wt = Wt4; K = 256; C = 64; i = gid - 65536; }
  else return;
  int c = i % C, k = i / C;
  Wt[(size_t)c * K + k] = f2bf(W[i]);
}

// ---------------- prescale: out = bf16(feat * ns[row]); row NN zeroed --------
__global__ __launch_bounds__(256) void prescale_kernel(
    const float* __restrict__ feat, const float* __restrict__ ns,
    unsigned short* __restrict__ out) {
  int idx = blockIdx.x * blockDim.x + threadIdx.x;
  if (idx >= (NN + 1) * 16) return;
  int row = idx >> 4;
  int c8 = (idx & 15) * 8;
  if (row == NN) {
    uint4 z = {0u, 0u, 0u, 0u};
    *reinterpret_cast<uint4*>(out + (size_t)row * 128 + c8) = z;
    return;
  }
  float sc = ns[row];
  float4 v0 = *reinterpret_cast<const float4*>(feat + (size_t)row * 128 + c8);
  float4 v1 = *reinterpret_cast<const float4*>(feat + (size_t)row * 128 + c8 + 4);
  union { unsigned short u[8]; uint4 v; } p;
  p.u[0] = f2bf(v0.x * sc); p.u[1] = f2bf(v0.y * sc);
  p.u[2] = f2bf(v0.z * sc); p.u[3] = f2bf(v0.w * sc);
  p.u[4] = f2bf(v1.x * sc); p.u[5] = f2bf(v1.y * sc);
  p.u[6] = f2bf(v1.z * sc); p.u[7] = f2bf(v1.w * sc);
  *reinterpret_cast<uint4*>(out + (size_t)row * 128 + c8) = p.v;
}

// ---------------- FUSED aggregate + GEMM ----------------
// Per block: stage Wt[128x128] in LDS; each of 4 waves gathers+aggregates 16
// of the block's 64 dst rows into swizzled a_lds (padded maskless CSR rows,
// 2-batch ILP); then MFMA and epilogue C = bf16((agg@W + b) * postscale).
__global__ __launch_bounds__(256) void agg_gemm_kernel(
    const unsigned short* __restrict__ x, const int* __restrict__ col,
    const int* __restrict__ row_off, const float* __restrict__ nd,
    const unsigned short* __restrict__ Wt, const float* __restrict__ bias,
    const float* __restrict__ postscale, unsigned short* __restrict__ Cout,
    int nN) {
  constexpr int K = 128, COLS = 128, TM = 64;
  constexpr int NT = COLS / 16;  // 8
  __shared__ unsigned short a_lds[TM * K];    // 16KB
  __shared__ unsigned short b_lds[COLS * K];  // 32KB
  const int row0 = blockIdx.x * TM;
  const int tid = threadIdx.x;
  const int wave = tid >> 6, lane = tid & 63;
  const int g = lane >> 3;   // 8 edge-subgroups
  const int lg = lane & 7;   // 32B chunk within row

  // stage Wt first: loads issue and fly under the gather phase
  for (int i = tid; i < COLS * K * 2 / 16; i += 256) {
    int byte_lin = i * 16;
    int r = byte_lin >> 8;
    int swz = byte_lin ^ ((r & 7) << 4);
    *reinterpret_cast<uint4*>((char*)b_lds + swz) =
        *reinterpret_cast<const uint4*>((const char*)Wt + byte_lin);
  }

  // aggregate: wave w owns rows w*16 .. w*16+15
#define ACC8(v0, v1)                                \
  acc[0] += unpk(v0.x); acc[1] += unpk(v0.y);       \
  acc[2] += unpk(v0.z); acc[3] += unpk(v0.w);       \
  acc[4] += unpk(v1.x); acc[5] += unpk(v1.y);       \
  acc[6] += unpk(v1.z); acc[7] += unpk(v1.w);

  for (int r = 0; r < 16; ++r) {
    const int lrow = wave * 16 + r;
    const int grow = row0 + lrow;
    f32x2 acc[8];
#pragma unroll
    for (int k = 0; k < 8; ++k) acc[k] = f32x2{0.f, 0.f};

    if (grow < nN) {
      const int beg = row_off[grow];
      const int end = row_off[grow + 1];
      for (int i0 = beg; i0 < end; i0 += 64) {
        const int rem = end - i0;
        int myc = (lane < rem) ? col[i0 + lane] : NN;
        const int nb = rem < 64 ? rem : 64;  // multiple of 8
        int j = 0;
        for (; j + 16 <= nb; j += 16) {
          int s0 = __shfl(myc, j + g);
          int s1 = __shfl(myc, j + 8 + g);
          const uint4* p0 = reinterpret_cast<const uint4*>(x + (size_t)s0 * 128 + lg * 16);
          const uint4* p1 = reinterpret_cast<const uint4*>(x + (size_t)s1 * 128 + lg * 16);
          uint4 a0 = p0[0];
          uint4 a1 = p0[1];
          uint4 b0 = p1[0];
          uint4 b1 = p1[1];
          ACC8(a0, a1);
          ACC8(b0, b1);
        }
        if (j < nb) {
          int s0 = __shfl(myc, j + g);
          const uint4* p0 = reinterpret_cast<const uint4*>(x + (size_t)s0 * 128 + lg * 16);
          uint4 a0 = p0[0];
          uint4 a1 = p0[1];
          ACC8(a0, a1);
        }
      }
    }
#pragma unroll
    for (int k = 0; k < 8; ++k) {
      acc[k].x += __shfl_xor(acc[k].x, 8);
      acc[k].y += __shfl_xor(acc[k].y, 8);
      acc[k].x += __shfl_xor(acc[k].x, 16);
      acc[k].y += __shfl_xor(acc[k].y, 16);
      acc[k].x += __shfl_xor(acc[k].x, 32);
      acc[k].y += __shfl_xor(acc[k].y, 32);
    }
    if (g == 0) {
      float sc = (grow < nN) ? nd[grow] : 0.0f;
      union { unsigned short u[16]; uint4 v[2]; } p;
#pragma unroll
      for (int k = 0; k < 8; ++k) {
        p.u[2 * k] = f2bf(acc[k].x * sc);
        p.u[2 * k + 1] = f2bf(acc[k].y * sc);
      }
      int base = lrow * 256 + lg * 32;
      int swzbit = (lrow & 7) << 4;
      *reinterpret_cast<uint4*>((char*)a_lds + (base ^ swzbit)) = p.v[0];
      *reinterpret_cast<uint4*>((char*)a_lds + ((base + 16) ^ swzbit)) = p.v[1];
    }
  }
#undef ACC8
  __syncthreads();

  // MFMA phase
  const int rrow = wave * 16 + (lane & 15);
  const int kofs = (lane >> 4) * 8;
  f32x4 facc[NT];
#pragma unroll
  for (int nt = 0; nt < NT; ++nt) facc[nt] = f32x4{0.f, 0.f, 0.f, 0.f};

  for (int ks = 0; ks < 4; ++ks) {
    const int k0 = ks * 32;
    int abyte = ((rrow * K + k0 + kofs) * 2) ^ ((rrow & 7) << 4);
    bf16x8 a = *reinterpret_cast<const bf16x8*>((const char*)a_lds + abyte);
#pragma unroll
    for (int nt = 0; nt < NT; ++nt) {
      int c = nt * 16 + (lane & 15);
      int bbyte = ((c * K + k0 + kofs) * 2) ^ ((c & 7) << 4);
      bf16x8 b = *reinterpret_cast<const bf16x8*>((const char*)b_lds + bbyte);
      facc[nt] = __builtin_amdgcn_mfma_f32_16x16x32_bf16(a, b, facc[nt], 0, 0, 0);
    }
  }

  __syncthreads();
#pragma unroll
  for (int nt = 0; nt < NT; ++nt) {
    int c = nt * 16 + (lane & 15);
    float bv = bias[c];
#pragma unroll
    for (int r = 0; r < 4; ++r) {
      int lrow = wave * 16 + (lane >> 4) * 4 + r;
      int grow = row0 + lrow;
      float ps = (postscale != nullptr && grow < nN) ? postscale[grow] : 1.0f;
      float v = (facc[nt][r] + bv) * ps;
      a_lds[lrow * COLS + c] = f2bf(v);
    }
  }
  __syncthreads();
  for (int i = tid; i < TM * COLS * 2 / 16; i += 256) {
    int byte_lin = i * 16;
    int r = byte_lin / (COLS * 2);
    int gr = row0 + r;
    if (gr < nN)
      *reinterpret_cast<uint4*>(Cout + (size_t)gr * COLS + (byte_lin % (COLS * 2)) / 2) =
          *reinterpret_cast<const uint4*>((const char*)a_lds + byte_lin);
  }
}

// ---------------- fused MLP + proj, LDS-staged B (80KB plan) ----------------
__global__ __launch_bounds__(256) void mlp_mfma_kernel(
    const unsigned short* __restrict__ H, const unsigned short* __restrict__ Wt3,
    const float* __restrict__ b3, const unsigned short* __restrict__ Wt4,
    const float* __restrict__ b4, float* __restrict__ Out, int nrows) {
  constexpr int TM = 64;
  __shared__ char smem[81920];
  unsigned short* h_lds = (unsigned short*)smem;
  char* bbuf[2] = {smem + 16384, smem + 32768};
  char* z_base = smem + 49152;
  const int row0 = blockIdx.x * TM;
  const int tid = threadIdx.x;
  const int wave = tid >> 6, lane = tid & 63;
  const int l15 = lane & 15;
  const int kofs = (lane >> 4) * 8;

  for (int i = tid; i < TM * 128 * 2 / 16; i += 256) {
    int byte_lin = i * 16;
    int r = byte_lin >> 8;
    int swz = byte_lin ^ ((r & 7) << 4);
    uint4 v = {0u, 0u, 0u, 0u};
    int gr = row0 + r;
    if (gr < nrows)
      v = *reinterpret_cast<const uint4*>(H + (size_t)gr * 128 + (byte_lin & 255) / 2);
    *reinterpret_cast<uint4*>((char*)h_lds + swz) = v;
  }

  auto stage_b3 = [&](int ks, char* dstb) {
#pragma unroll
    for (int it = 0; it < 4; ++it) {
      int byte_lin = (tid + it * 256) * 16;
      int r = byte_lin >> 6;
      int kb = byte_lin & 63;
      int swz = byte_lin ^ (((r >> 1) & 3) << 4);
      *reinterpret_cast<uint4*>(dstb + swz) =
          *reinterpret_cast<const uint4*>((const char*)Wt3 + r * 256 + ks * 64 + kb);
    }
  };
  stage_b3(0, bbuf[0]);
  __syncthreads();

  const int rrow = wave * 16 + l15;
  {
    f32x4 acc[16];
#pragma unroll
    for (int nt = 0; nt < 16; ++nt) acc[nt] = f32x4{0.f, 0.f, 0.f, 0.f};
    for (int ks = 0; ks < 4; ++ks) {
      if (ks < 3) stage_b3(ks + 1, bbuf[(ks + 1) & 1]);
      const char* bl = bbuf[ks & 1];
      int abyte = ((rrow * 128 + ks * 32 + kofs) * 2) ^ ((rrow & 7) << 4);
      bf16x8 a = *reinterpret_cast<const bf16x8*>((const char*)h_lds + abyte);
#pragma unroll
      for (int nt = 0; nt < 16; ++nt) {
        int c = nt * 16 + l15;
        int bbyte = (c * 64 + (kofs / 8) * 16) ^ (((c >> 1) & 3) << 4);
        bf16x8 b = *reinterpret_cast<const bf16x8*>(bl + bbyte);
        acc[nt] = __builtin_amdgcn_mfma_f32_16x16x32_bf16(a, b, acc[nt], 0, 0, 0);
      }
      __syncthreads();
    }
#pragma unroll
    for (int nt = 0; nt < 16; ++nt) {
      int c = nt * 16 + l15;
      float bv = b3[c];
#pragma unroll
      for (int r = 0; r < 4; ++r) {
        int lrow = wave * 16 + (lane >> 4) * 4 + r;
        float v = fmaxf(acc[nt][r] + bv, 0.0f);
        int zb = (lrow * 512 + c * 2) ^ ((lrow & 7) << 4);
        *reinterpret_cast<unsigned short*>(z_base + zb) = f2bf(v);
      }
    }
  }
  __syncthreads();

  char* w4 = smem;
  for (int it = 0; it < 8; ++it) {
    int byte_lin = (tid + it * 256) * 16;
    int r = byte_lin >> 9;
    int swz = byte_lin ^ ((r & 7) << 4);
    *reinterpret_cast<uint4*>(w4 + swz) =
        *reinterpret_cast<const uint4*>((const char*)Wt4 + byte_lin);
  }
  __syncthreads();

  f32x4 acc2[4];
#pragma unroll
  for (int nt = 0; nt < 4; ++nt) acc2[nt] = f32x4{0.f, 0.f, 0.f, 0.f};
  for (int ks = 0; ks < 8; ++ks) {
    const int k0 = ks * 32;
    int zbyte = ((rrow * 256 + k0 + kofs) * 2) ^ ((rrow & 7) << 4);
    bf16x8 a = *reinterpret_cast<const bf16x8*>(z_base + zbyte);
#pragma unroll
    for (int nt = 0; nt < 4; ++nt) {
      int c = nt * 16 + l15;
      int wbyte = (c * 512 + (k0 + kofs) * 2) ^ ((c & 7) << 4);
      bf16x8 b = *reinterpret_cast<const bf16x8*>(w4 + wbyte);
      acc2[nt] = __builtin_amdgcn_mfma_f32_16x16x32_bf16(a, b, acc2[nt], 0, 0, 0);
    }
  }
#pragma unroll
  for (int nt = 0; nt < 4; ++nt) {
    float bv = b4[nt * 16 + l15];
#pragma unroll
    for (int r = 0; r < 4; ++r) acc2[nt][r] += bv;
  }

  float rinv[4];
#pragma unroll
  for (int r = 0; r < 4; ++r) {
    float ss = 0.0f;
#pragma unroll
    for (int nt = 0; nt < 4; ++nt) ss = fmaf(acc2[nt][r], acc2[nt][r], ss);
    ss += __shfl_xor(ss, 1);
    ss += __shfl_xor(ss, 2);
    ss += __shfl_xor(ss, 4);
    ss += __shfl_xor(ss, 8);
    rinv[r] = rsqrtf(ss);
  }
#pragma unroll
  for (int nt = 0; nt < 4; ++nt) {
    int c = nt * 16 + l15;
#pragma unroll
    for (int r = 0; r < 4; ++r) {
      int grow = row0 + wave * 16 + (lane >> 4) * 4 + r;
      if (grow < nrows)
        Out[(size_t)grow * 64 + c] = fmaxf(1e-6f, fabsf(acc2[nt][r]) * rinv[r]);
    }
  }
}

extern "C" void kernel_launch(void* const* d_in, const int* in_sizes, int n_in,
                              void* d_out, int out_size, void* d_ws, size_t ws_size,
                              hipStream_t stream) {
  const float* feat = (const float*)d_in[0];
  const int* src = (const int*)d_in[1];
  const int* dst = (const int*)d_in[2];
  const float* W1 = (const float*)d_in[3];
  const float* b1 = (const float*)d_in[4];
  const float* W2 = (const float*)d_in[5];
  const float* b2 = (const float*)d_in[6];
  const float* W3 = (const float*)d_in[7];
  const float* b3 = (const float*)d_in[8];
  const float* W4 = (const float*)d_in[9];
  const float* b4 = (const float*)d_in[10];
  float* out = (float*)d_out;

  char* ws = (char*)d_ws;
  size_t off = 0;
  auto alloc = [&](size_t bytes) {
    size_t p = off;
    off = (off + bytes + 255) & ~(size_t)255;
    return p;
  };
  float* ns = (float*)(ws + alloc((size_t)NN * 4));
  float* nd = (float*)(ws + alloc((size_t)NN * 4));
  int* row_off = (int*)(ws + alloc((size_t)(NN + 64) * 4));
  int* col = (int*)(ws + alloc((size_t)(NE + 8 * NN + 64) * 4));  // padded CSR
  unsigned short* Wt1 = (unsigned short*)(ws + alloc((size_t)128 * 128 * 2));
  unsigned short* Wt2 = (unsigned short*)(ws + alloc((size_t)128 * 128 * 2));
  unsigned short* Wt3 = (unsigned short*)(ws + alloc((size_t)256 * 128 * 2));
  unsigned short* Wt4 = (unsigned short*)(ws + alloc((size_t)64 * 256 * 2));
  unsigned short* B0 = (unsigned short*)(ws + alloc((size_t)(NN + 1) * 128 * 2));
  unsigned short* B1 = (unsigned short*)(ws + alloc((size_t)(NN + 1) * 128 * 2));

  // CSR build temps: in B0 (dead until prescale) and B1 (dead until fused L1)
  int* degO = (int*)B0;
  int* degI = degO + NN;
  int* blk = degI + NN;        // 128 ints
  int* dpad = blk + 128;       // NN+1 ints
  int* C = (int*)B1;           // [32][NN] = 12.8MB (first half of B1)

  hipMemsetAsync(degO, 0, (size_t)NN * 4, stream);
  // zero dummy row NN of B1 (gather target for padded edges in layer 2)
  hipMemsetAsync(B1 + (size_t)NN * 128, 0, 256, stream);

  histsrc_kernel<<<256, 256, 0, stream>>>(src, degO);
  histdst_kernel<<<256, 256, 0, stream>>>(dst, C);
  chunkscan_kernel<<<(NN + 255) / 256, 256, 0, stream>>>(C, degO, degI, dpad, ns, nd);
  const int nblk = (NN + 1 + 1023) / 1024;  // 99
  scan1_kernel<<<nblk, 1024, 0, stream>>>(dpad, row_off, blk, NN + 1);
  scan2_kernel<<<1, 128, 0, stream>>>(blk, nblk);
  scan3_kernel<<<nblk, 1024, 0, stream>>>(row_off, blk, NN + 1);
  padfill_kernel<<<(NN + 255) / 256, 256, 0, stream>>>(row_off, degI, col);
  scatter2_kernel<<<256, 256, 0, stream>>>(src, dst, row_off, C, col);

  wconv_all_kernel<<<320, 256, 0, stream>>>(W1, Wt1, W2, Wt2, W3, Wt3, W4, Wt4);

  const int nGemmBlk = (NN + 63) / 64;

  // B0 = bf16(feat * ns) (+ zero row NN)
  prescale_kernel<<<((NN + 1) * 16 + 255) / 256, 256, 0, stream>>>(feat, ns, B0);
  // layer 1 fused: B1 = bf16((agg(B0)*nd @ W1 + b1) * ns)
  agg_gemm_kernel<<<nGemmBlk, 256, 0, stream>>>(B0, col, row_off, nd, Wt1, b1, ns, B1, NN);
  // layer 2 fused: B0 = bf16(agg(B1)*nd @ W2 + b2)
  agg_gemm_kernel<<<nGemmBlk, 256, 0, stream>>>(B1, col, row_off, nd, Wt2, b2, nullptr, B0, NN);
  // MLP + proj
  mlp_mfma_kernel<<<nGemmBlk, 256, 0, stream>>>(B0, Wt3, b3, Wt4, b4, out, NN);
}

// Round 12
// 353.423 us; speedup vs baseline: 1.1839x; 1.1839x over previous
//
#include <hip/hip_runtime.h>

#define NN 100000
#define NE 1600000
#define WIN 12500

typedef __bf16 bf16x8 __attribute__((ext_vector_type(8)));
typedef float f32x4 __attribute__((ext_vector_type(4)));
typedef float f32x2 __attribute__((ext_vector_type(2)));

static __device__ __forceinline__ unsigned short f2bf(float f) {
  unsigned int u = __float_as_uint(f);
  unsigned int r = (u + 0x7fff + ((u >> 16) & 1)) >> 16;  // RNE
  return (unsigned short)r;
}
static __device__ __forceinline__ f32x2 unpk(unsigned int u) {
  f32x2 r;
  r.x = __uint_as_float(u << 16);
  r.y = __uint_as_float(u & 0xffff0000u);
  return r;
}

// ---------------- combined degree histograms ----------------
// 512 blocks: bit0 = src/dst, bits1-3 = window, bits4-8 = chunk.
// src: LDS hist -> coalesced atomic merge into degO.
// dst: LDS hist -> plain per-chunk store C[chunk][node].
__global__ __launch_bounds__(256) void histboth_kernel(
    const int* __restrict__ src, const int* __restrict__ dst,
    int* __restrict__ degO, int* __restrict__ C) {
  __shared__ int hist[WIN];
  const int isdst = blockIdx.x & 1;
  const int win = (blockIdx.x >> 1) & 7;
  const int chunk = blockIdx.x >> 4;  // 0..31
  const int w0 = win * WIN;
  const int w1 = w0 + WIN;
  const int* __restrict__ arr = isdst ? dst : src;
  for (int i = threadIdx.x; i < WIN; i += 256) hist[i] = 0;
  __syncthreads();
  const int per = NE / 32;  // 50000
  const int e0 = chunk * per;
  const int e1 = e0 + per;
  for (int e = e0 + threadIdx.x * 4; e + 3 < e1; e += 256 * 4) {
    int4 v = *reinterpret_cast<const int4*>(arr + e);
    if (v.x >= w0 && v.x < w1) atomicAdd(&hist[v.x - w0], 1);
    if (v.y >= w0 && v.y < w1) atomicAdd(&hist[v.y - w0], 1);
    if (v.z >= w0 && v.z < w1) atomicAdd(&hist[v.z - w0], 1);
    if (v.w >= w0 && v.w < w1) atomicAdd(&hist[v.w - w0], 1);
  }
  __syncthreads();
  if (isdst) {
    for (int i = threadIdx.x; i < WIN; i += 256)
      C[(size_t)chunk * NN + w0 + i] = hist[i];
  } else {
    for (int i = threadIdx.x; i < WIN; i += 256) {
      int c = hist[i];
      if (c) atomicAdd(&degO[w0 + i], c);
    }
  }
}

// ---------------- chunk-scan + true degI + padded deg + fused norms ----------------
__global__ __launch_bounds__(256) void chunkscan_kernel(
    int* __restrict__ C, const int* __restrict__ degO,
    int* __restrict__ degI, int* __restrict__ dpad,
    float* __restrict__ ns, float* __restrict__ nd) {
  int n = blockIdx.x * blockDim.x + threadIdx.x;
  if (n >= NN) return;
  int acc = 0;
#pragma unroll
  for (int c = 0; c < 32; ++c) {
    int t = C[(size_t)c * NN + n];
    C[(size_t)c * NN + n] = acc;
    acc += t;
  }
  degI[n] = acc;
  dpad[n] = (acc + 7) & ~7;
  nd[n] = rsqrtf(fmaxf((float)acc, 1.0f));
  ns[n] = rsqrtf(fmaxf((float)degO[n], 1.0f));
  if (n == 0) dpad[NN] = 0;
}

// ---------------- prefix scan (over NN+1 entries of dpad) ----------------
__global__ __launch_bounds__(1024) void scan1_kernel(
    const int* __restrict__ deg, int* __restrict__ excl,
    int* __restrict__ blk, int n) {
  __shared__ int lds[1024];
  const int tid = threadIdx.x;
  const int gid = blockIdx.x * 1024 + tid;
  int v = (gid < n) ? deg[gid] : 0;
  lds[tid] = v;
  __syncthreads();
  for (int off = 1; off < 1024; off <<= 1) {
    int t = (tid >= off) ? lds[tid - off] : 0;
    __syncthreads();
    lds[tid] += t;
    __syncthreads();
  }
  if (gid < n) excl[gid] = lds[tid] - v;
  if (tid == 1023) blk[blockIdx.x] = lds[1023];
}

__global__ __launch_bounds__(128) void scan2_kernel(int* __restrict__ blk, int nblk) {
  __shared__ int lds[128];
  const int tid = threadIdx.x;
  int v = (tid < nblk) ? blk[tid] : 0;
  lds[tid] = v;
  __syncthreads();
  for (int off = 1; off < 128; off <<= 1) {
    int t = (tid >= off) ? lds[tid - off] : 0;
    __syncthreads();
    lds[tid] += t;
    __syncthreads();
  }
  if (tid < nblk) blk[tid] = lds[tid] - v;
}

__global__ __launch_bounds__(1024) void scan3_kernel(
    int* __restrict__ row_off, const int* __restrict__ blk, int n) {
  int gid = blockIdx.x * 1024 + threadIdx.x;
  if (gid < n) row_off[gid] += blk[gid >> 10];
}

// ---------------- scatter via LDS cursors + fused pad fill ----------------
// 256 blocks = 8 windows x 32 chunks; cursor = row_off + C[chunk] (exclusive).
// chunk-0 blocks also fill their window's pad slots (disjoint from all
// chunks' scatter regions, so no ordering hazard).
__global__ __launch_bounds__(256) void scatter2_kernel(
    const int* __restrict__ src, const int* __restrict__ dst,
    const int* __restrict__ row_off, const int* __restrict__ degI,
    const int* __restrict__ C, int* __restrict__ col) {
  __shared__ int cur[WIN];
  const int win = blockIdx.x & 7;
  const int chunk = blockIdx.x >> 3;  // 0..31
  const int w0 = win * WIN;
  const int w1 = w0 + WIN;
  for (int i = threadIdx.x; i < WIN; i += 256)
    cur[i] = row_off[w0 + i] + C[(size_t)chunk * NN + w0 + i];
  __syncthreads();
  const int per = NE / 32;
  const int e0 = chunk * per;
  const int e1 = e0 + per;
  for (int e = e0 + threadIdx.x * 4; e + 3 < e1; e += 256 * 4) {
    int4 d4 = *reinterpret_cast<const int4*>(dst + e);
    int4 s4 = *reinterpret_cast<const int4*>(src + e);
    if (d4.x >= w0 && d4.x < w1) col[atomicAdd(&cur[d4.x - w0], 1)] = s4.x;
    if (d4.y >= w0 && d4.y < w1) col[atomicAdd(&cur[d4.y - w0], 1)] = s4.y;
    if (d4.z >= w0 && d4.z < w1) col[atomicAdd(&cur[d4.z - w0], 1)] = s4.z;
    if (d4.w >= w0 && d4.w < w1) col[atomicAdd(&cur[d4.w - w0], 1)] = s4.w;
  }
  if (chunk == 0) {
    for (int n = w0 + threadIdx.x; n < w1; n += 256) {
      int e = row_off[n] + degI[n];
      int ee = row_off[n + 1];
      for (; e < ee; ++e) col[e] = NN;
    }
  }
}

// ---------------- all weights transpose+convert in one launch ----------------
__global__ __launch_bounds__(256) void wconv_all_kernel(
    const float* __restrict__ W1, unsigned short* __restrict__ Wt1,
    const float* __restrict__ W2, unsigned short* __restrict__ Wt2,
    const float* __restrict__ W3, unsigned short* __restrict__ Wt3,
    const float* __restrict__ W4, unsigned short* __restrict__ Wt4) {
  int gid = blockIdx.x * blockDim.x + threadIdx.x;
  const float* W;
  unsigned short* Wt;
  int K, C, i;
  if (gid < 16384) { W = W1; Wt = Wt1; K = 128; C = 128; i = gid; }
  else if (gid < 32768) { W = W2; Wt = Wt2; K = 128; C = 128; i = gid - 16384; }
  else if (gid < 65536) { W = W3; Wt = Wt3; K = 128; C = 256; i = gid - 32768; }
  else if (gid < 81920) { W = W4; Wt = Wt4; K = 256; C = 64; i = gid - 65536; }
  else return;
  int c = i % C, k = i / C;
  Wt[(size_t)c * K + k] = f2bf(W[i]);
}

// ---------------- prescale: out = bf16(feat * ns[row]); row NN zeroed --------
__global__ __launch_bounds__(256) void prescale_kernel(
    const float* __restrict__ feat, const float* __restrict__ ns,
    unsigned short* __restrict__ out) {
  int idx = blockIdx.x * blockDim.x + threadIdx.x;
  if (idx >= (NN + 1) * 16) return;
  int row = idx >> 4;
  int c8 = (idx & 15) * 8;
  if (row == NN) {
    uint4 z = {0u, 0u, 0u, 0u};
    *reinterpret_cast<uint4*>(out + (size_t)row * 128 + c8) = z;
    return;
  }
  float sc = ns[row];
  float4 v0 = *reinterpret_cast<const float4*>(feat + (size_t)row * 128 + c8);
  float4 v1 = *reinterpret_cast<const float4*>(feat + (size_t)row * 128 + c8 + 4);
  union { unsigned short u[8]; uint4 v; } p;
  p.u[0] = f2bf(v0.x * sc); p.u[1] = f2bf(v0.y * sc);
  p.u[2] = f2bf(v0.z * sc); p.u[3] = f2bf(v0.w * sc);
  p.u[4] = f2bf(v1.x * sc); p.u[5] = f2bf(v1.y * sc);
  p.u[6] = f2bf(v1.z * sc); p.u[7] = f2bf(v1.w * sc);
  *reinterpret_cast<uint4*>(out + (size_t)row * 128 + c8) = p.v;
}

// ---------------- CSR gather: out[d] = bf16(nd[d] * sum x[s]) ----------------
// padded rows (mult of 8, dummy->row NN zeros): maskless; 2 batches in flight.
__global__ __launch_bounds__(256) void agg_bf16_kernel(
    const unsigned short* __restrict__ x, const int* __restrict__ col,
    const int* __restrict__ row_off, const float* __restrict__ nd,
    unsigned short* __restrict__ out, int nN) {
  const int wid = (blockIdx.x * blockDim.x + threadIdx.x) >> 6;
  const int lane = threadIdx.x & 63;
  if (wid >= nN) return;
  const int beg = row_off[wid];
  const int end = row_off[wid + 1];
  const int g = lane >> 3;
  const int lg = lane & 7;

  f32x2 acc[8];
#pragma unroll
  for (int k = 0; k < 8; ++k) acc[k] = f32x2{0.f, 0.f};

#define ACC8(v0, v1)                                \
  acc[0] += unpk(v0.x); acc[1] += unpk(v0.y);       \
  acc[2] += unpk(v0.z); acc[3] += unpk(v0.w);       \
  acc[4] += unpk(v1.x); acc[5] += unpk(v1.y);       \
  acc[6] += unpk(v1.z); acc[7] += unpk(v1.w);

  for (int i0 = beg; i0 < end; i0 += 64) {
    const int rem = end - i0;
    int myc = (lane < rem) ? col[i0 + lane] : NN;
    const int nb = rem < 64 ? rem : 64;  // multiple of 8
    int j = 0;
    for (; j + 16 <= nb; j += 16) {
      int s0 = __shfl(myc, j + g);
      int s1 = __shfl(myc, j + 8 + g);
      const uint4* p0 = reinterpret_cast<const uint4*>(x + (size_t)s0 * 128 + lg * 16);
      const uint4* p1 = reinterpret_cast<const uint4*>(x + (size_t)s1 * 128 + lg * 16);
      uint4 a0 = p0[0];
      uint4 a1 = p0[1];
      uint4 b0 = p1[0];
      uint4 b1 = p1[1];
      ACC8(a0, a1);
      ACC8(b0, b1);
    }
    if (j < nb) {
      int s0 = __shfl(myc, j + g);
      const uint4* p0 = reinterpret_cast<const uint4*>(x + (size_t)s0 * 128 + lg * 16);
      uint4 a0 = p0[0];
      uint4 a1 = p0[1];
      ACC8(a0, a1);
    }
  }
#undef ACC8

#pragma unroll
  for (int k = 0; k < 8; ++k) {
    acc[k].x += __shfl_xor(acc[k].x, 8);
    acc[k].y += __shfl_xor(acc[k].y, 8);
    acc[k].x += __shfl_xor(acc[k].x, 16);
    acc[k].y += __shfl_xor(acc[k].y, 16);
    acc[k].x += __shfl_xor(acc[k].x, 32);
    acc[k].y += __shfl_xor(acc[k].y, 32);
  }
  if (g == 0) {
    float sc = nd[wid];
    union { unsigned short u[16]; uint4 v[2]; } p;
#pragma unroll
    for (int k = 0; k < 8; ++k) {
      p.u[2 * k] = f2bf(acc[k].x * sc);
      p.u[2 * k + 1] = f2bf(acc[k].y * sc);
    }
    uint4* o = reinterpret_cast<uint4*>(out + (size_t)wid * 128 + lg * 16);
    o[0] = p.v[0];
    o[1] = p.v[1];
  }
}

// ---------------- MFMA GEMM with LDS-staged B ----------------
__global__ __launch_bounds__(256) void gemm_mfma_kernel(
    const unsigned short* __restrict__ A, const unsigned short* __restrict__ Wt,
    const float* __restrict__ bias, const float* __restrict__ postscale,
    unsigned short* __restrict__ C, int nrows) {
  constexpr int K = 128, COLS = 128, TM = 64;
  constexpr int NT = COLS / 16;  // 8
  __shared__ unsigned short a_lds[TM * K];
  __shared__ unsigned short b_lds[COLS * K];
  const int row0 = blockIdx.x * TM;
  const int tid = threadIdx.x;
  const int wave = tid >> 6, lane = tid & 63;

  for (int i = tid; i < TM * K * 2 / 16; i += 256) {
    int byte_lin = i * 16;
    int r = byte_lin >> 8;
    int swz = byte_lin ^ ((r & 7) << 4);
    uint4 v = {0u, 0u, 0u, 0u};
    int gr = row0 + r;
    if (gr < nrows)
      v = *reinterpret_cast<const uint4*>(A + (size_t)gr * K + (byte_lin & 255) / 2);
    *reinterpret_cast<uint4*>((char*)a_lds + swz) = v;
  }
  for (int i = tid; i < COLS * K * 2 / 16; i += 256) {
    int byte_lin = i * 16;
    int r = byte_lin >> 8;
    int swz = byte_lin ^ ((r & 7) << 4);
    *reinterpret_cast<uint4*>((char*)b_lds + swz) =
        *reinterpret_cast<const uint4*>((const char*)Wt + byte_lin);
  }
  __syncthreads();

  const int rrow = wave * 16 + (lane & 15);
  const int kofs = (lane >> 4) * 8;
  f32x4 acc[NT];
#pragma unroll
  for (int nt = 0; nt < NT; ++nt) acc[nt] = f32x4{0.f, 0.f, 0.f, 0.f};

  for (int ks = 0; ks < 4; ++ks) {
    const int k0 = ks * 32;
    int abyte = ((rrow * K + k0 + kofs) * 2) ^ ((rrow & 7) << 4);
    bf16x8 a = *reinterpret_cast<const bf16x8*>((const char*)a_lds + abyte);
#pragma unroll
    for (int nt = 0; nt < NT; ++nt) {
      int c = nt * 16 + (lane & 15);
      int bbyte = ((c * K + k0 + kofs) * 2) ^ ((c & 7) << 4);
      bf16x8 b = *reinterpret_cast<const bf16x8*>((const char*)b_lds + bbyte);
      acc[nt] = __builtin_amdgcn_mfma_f32_16x16x32_bf16(a, b, acc[nt], 0, 0, 0);
    }
  }

  __syncthreads();
#pragma unroll
  for (int nt = 0; nt < NT; ++nt) {
    int c = nt * 16 + (lane & 15);
    float bv = bias[c];
#pragma unroll
    for (int r = 0; r < 4; ++r) {
      int lrow = wave * 16 + (lane >> 4) * 4 + r;
      int grow = row0 + lrow;
      float ps = (postscale != nullptr && grow < nrows) ? postscale[grow] : 1.0f;
      float v = (acc[nt][r] + bv) * ps;
      a_lds[lrow * COLS + c] = f2bf(v);
    }
  }
  __syncthreads();
  for (int i = tid; i < TM * COLS * 2 / 16; i += 256) {
    int byte_lin = i * 16;
    int r = byte_lin / (COLS * 2);
    int gr = row0 + r;
    if (gr < nrows)
      *reinterpret_cast<uint4*>(C + (size_t)gr * COLS + (byte_lin % (COLS * 2)) / 2) =
          *reinterpret_cast<const uint4*>((const char*)a_lds + byte_lin);
  }
}

// ---------------- fused MLP + proj, LDS-staged B (80KB plan) ----------------
__global__ __launch_bounds__(256) void mlp_mfma_kernel(
    const unsigned short* __restrict__ H, const unsigned short* __restrict__ Wt3,
    const float* __restrict__ b3, const unsigned short* __restrict__ Wt4,
    const float* __restrict__ b4, float* __restrict__ Out, int nrows) {
  constexpr int TM = 64;
  __shared__ char smem[81920];
  unsigned short* h_lds = (unsigned short*)smem;
  char* bbuf[2] = {smem + 16384, smem + 32768};
  char* z_base = smem + 49152;
  const int row0 = blockIdx.x * TM;
  const int tid = threadIdx.x;
  const int wave = tid >> 6, lane = tid & 63;
  const int l15 = lane & 15;
  const int kofs = (lane >> 4) * 8;

  for (int i = tid; i < TM * 128 * 2 / 16; i += 256) {
    int byte_lin = i * 16;
    int r = byte_lin >> 8;
    int swz = byte_lin ^ ((r & 7) << 4);
    uint4 v = {0u, 0u, 0u, 0u};
    int gr = row0 + r;
    if (gr < nrows)
      v = *reinterpret_cast<const uint4*>(H + (size_t)gr * 128 + (byte_lin & 255) / 2);
    *reinterpret_cast<uint4*>((char*)h_lds + swz) = v;
  }

  auto stage_b3 = [&](int ks, char* dstb) {
#pragma unroll
    for (int it = 0; it < 4; ++it) {
      int byte_lin = (tid + it * 256) * 16;
      int r = byte_lin >> 6;
      int kb = byte_lin & 63;
      int swz = byte_lin ^ (((r >> 1) & 3) << 4);
      *reinterpret_cast<uint4*>(dstb + swz) =
          *reinterpret_cast<const uint4*>((const char*)Wt3 + r * 256 + ks * 64 + kb);
    }
  };
  stage_b3(0, bbuf[0]);
  __syncthreads();

  const int rrow = wave * 16 + l15;
  {
    f32x4 acc[16];
#pragma unroll
    for (int nt = 0; nt < 16; ++nt) acc[nt] = f32x4{0.f, 0.f, 0.f, 0.f};
    for (int ks = 0; ks < 4; ++ks) {
      if (ks < 3) stage_b3(ks + 1, bbuf[(ks + 1) & 1]);
      const char* bl = bbuf[ks & 1];
      int abyte = ((rrow * 128 + ks * 32 + kofs) * 2) ^ ((rrow & 7) << 4);
      bf16x8 a = *reinterpret_cast<const bf16x8*>((const char*)h_lds + abyte);
#pragma unroll
      for (int nt = 0; nt < 16; ++nt) {
        int c = nt * 16 + l15;
        int bbyte = (c * 64 + (kofs / 8) * 16) ^ (((c >> 1) & 3) << 4);
        bf16x8 b = *reinterpret_cast<const bf16x8*>(bl + bbyte);
        acc[nt] = __builtin_amdgcn_mfma_f32_16x16x32_bf16(a, b, acc[nt], 0, 0, 0);
      }
      __syncthreads();
    }
#pragma unroll
    for (int nt = 0; nt < 16; ++nt) {
      int c = nt * 16 + l15;
      float bv = b3[c];
#pragma unroll
      for (int r = 0; r < 4; ++r) {
        int lrow = wave * 16 + (lane >> 4) * 4 + r;
        float v = fmaxf(acc[nt][r] + bv, 0.0f);
        int zb = (lrow * 512 + c * 2) ^ ((lrow & 7) << 4);
        *reinterpret_cast<unsigned short*>(z_base + zb) = f2bf(v);
      }
    }
  }
  __syncthreads();

  char* w4 = smem;
  for (int it = 0; it < 8; ++it) {
    int byte_lin = (tid + it * 256) * 16;
    int r = byte_lin >> 9;
    int swz = byte_lin ^ ((r & 7) << 4);
    *reinterpret_cast<uint4*>(w4 + swz) =
        *reinterpret_cast<const uint4*>((const char*)Wt4 + byte_lin);
  }
  __syncthreads();

  f32x4 acc2[4];
#pragma unroll
  for (int nt = 0; nt < 4; ++nt) acc2[nt] = f32x4{0.f, 0.f, 0.f, 0.f};
  for (int ks = 0; ks < 8; ++ks) {
    const int k0 = ks * 32;
    int zbyte = ((rrow * 256 + k0 + kofs) * 2) ^ ((rrow & 7) << 4);
    bf16x8 a = *reinterpret_cast<const bf16x8*>(z_base + zbyte);
#pragma unroll
    for (int nt = 0; nt < 4; ++nt) {
      int c = nt * 16 + l15;
      int wbyte = (c * 512 + (k0 + kofs) * 2) ^ ((c & 7) << 4);
      bf16x8 b = *reinterpret_cast<const bf16x8*>(w4 + wbyte);
      acc2[nt] = __builtin_amdgcn_mfma_f32_16x16x32_bf16(a, b, acc2[nt], 0, 0, 0);
    }
  }
#pragma unroll
  for (int nt = 0; nt < 4; ++nt) {
    float bv = b4[nt * 16 + l15];
#pragma unroll
    for (int r = 0; r < 4; ++r) acc2[nt][r] += bv;
  }

  float rinv[4];
#pragma unroll
  for (int r = 0; r < 4; ++r) {
    float ss = 0.0f;
#pragma unroll
    for (int nt = 0; nt < 4; ++nt) ss = fmaf(acc2[nt][r], acc2[nt][r], ss);
    ss += __shfl_xor(ss, 1);
    ss += __shfl_xor(ss, 2);
    ss += __shfl_xor(ss, 4);
    ss += __shfl_xor(ss, 8);
    rinv[r] = rsqrtf(ss);
  }
#pragma unroll
  for (int nt = 0; nt < 4; ++nt) {
    int c = nt * 16 + l15;
#pragma unroll
    for (int r = 0; r < 4; ++r) {
      int grow = row0 + wave * 16 + (lane >> 4) * 4 + r;
      if (grow < nrows)
        Out[(size_t)grow * 64 + c] = fmaxf(1e-6f, fabsf(acc2[nt][r]) * rinv[r]);
    }
  }
}

extern "C" void kernel_launch(void* const* d_in, const int* in_sizes, int n_in,
                              void* d_out, int out_size, void* d_ws, size_t ws_size,
                              hipStream_t stream) {
  const float* feat = (const float*)d_in[0];
  const int* src = (const int*)d_in[1];
  const int* dst = (const int*)d_in[2];
  const float* W1 = (const float*)d_in[3];
  const float* b1 = (const float*)d_in[4];
  const float* W2 = (const float*)d_in[5];
  const float* b2 = (const float*)d_in[6];
  const float* W3 = (const float*)d_in[7];
  const float* b3 = (const float*)d_in[8];
  const float* W4 = (const float*)d_in[9];
  const float* b4 = (const float*)d_in[10];
  float* out = (float*)d_out;

  char* ws = (char*)d_ws;
  size_t off = 0;
  auto alloc = [&](size_t bytes) {
    size_t p = off;
    off = (off + bytes + 255) & ~(size_t)255;
    return p;
  };
  float* ns = (float*)(ws + alloc((size_t)NN * 4));
  float* nd = (float*)(ws + alloc((size_t)NN * 4));
  int* row_off = (int*)(ws + alloc((size_t)(NN + 64) * 4));
  int* col = (int*)(ws + alloc((size_t)(NE + 8 * NN + 64) * 4));  // padded CSR
  unsigned short* Wt1 = (unsigned short*)(ws + alloc((size_t)128 * 128 * 2));
  unsigned short* Wt2 = (unsigned short*)(ws + alloc((size_t)128 * 128 * 2));
  unsigned short* Wt3 = (unsigned short*)(ws + alloc((size_t)256 * 128 * 2));
  unsigned short* Wt4 = (unsigned short*)(ws + alloc((size_t)64 * 256 * 2));
  unsigned short* B0 = (unsigned short*)(ws + alloc((size_t)(NN + 1) * 128 * 2));
  unsigned short* B1 = (unsigned short*)(ws + alloc((size_t)(NN + 1) * 128 * 2));

  // CSR build temps: in B0 (dead until prescale) and B1 (dead until agg1)
  int* degO = (int*)B0;
  int* degI = degO + NN;
  int* blk = degI + NN;        // 128 ints
  int* dpad = blk + 128;       // NN+1 ints
  int* C = (int*)B1;           // [32][NN] = 12.8MB

  hipMemsetAsync(degO, 0, (size_t)NN * 4, stream);

  histboth_kernel<<<512, 256, 0, stream>>>(src, dst, degO, C);
  chunkscan_kernel<<<(NN + 255) / 256, 256, 0, stream>>>(C, degO, degI, dpad, ns, nd);
  const int nblk = (NN + 1 + 1023) / 1024;  // 99
  scan1_kernel<<<nblk, 1024, 0, stream>>>(dpad, row_off, blk, NN + 1);
  scan2_kernel<<<1, 128, 0, stream>>>(blk, nblk);
  scan3_kernel<<<nblk, 1024, 0, stream>>>(row_off, blk, NN + 1);
  scatter2_kernel<<<256, 256, 0, stream>>>(src, dst, row_off, degI, C, col);

  wconv_all_kernel<<<320, 256, 0, stream>>>(W1, Wt1, W2, Wt2, W3, Wt3, W4, Wt4);

  const int nGemmBlk = (NN + 63) / 64;
  const int aggBlocks = (NN * 64 + 255) / 256;

  prescale_kernel<<<((NN + 1) * 16 + 255) / 256, 256, 0, stream>>>(feat, ns, B0);
  agg_bf16_kernel<<<aggBlocks, 256, 0, stream>>>(B0, col, row_off, nd, B1, NN);
  gemm_mfma_kernel<<<nGemmBlk, 256, 0, stream>>>(B1, Wt1, b1, ns, B0, NN);
  agg_bf16_kernel<<<aggBlocks, 256, 0, stream>>>(B0, col, row_off, nd, B1, NN);
  gemm_mfma_kernel<<<nGemmBlk, 256, 0, stream>>>(B1, Wt2, b2, nullptr, B0, NN);
  mlp_mfma_kernel<<<nGemmBlk, 256, 0, stream>>>(B0, Wt3, b3, Wt4, b4, out, NN);
}

// Round 13
// 347.570 us; speedup vs baseline: 1.2039x; 1.0168x over previous
//
#include <hip/hip_runtime.h>

#define NN 100000
#define NE 1600000
#define WIN 12500
#define NCHUNK 64

typedef __bf16 bf16x8 __attribute__((ext_vector_type(8)));
typedef float f32x4 __attribute__((ext_vector_type(4)));
typedef float f32x2 __attribute__((ext_vector_type(2)));

static __device__ __forceinline__ unsigned short f2bf(float f) {
  unsigned int u = __float_as_uint(f);
  unsigned int r = (u + 0x7fff + ((u >> 16) & 1)) >> 16;  // RNE
  return (unsigned short)r;
}
static __device__ __forceinline__ f32x2 unpk(unsigned int u) {
  f32x2 r;
  r.x = __uint_as_float(u << 16);
  r.y = __uint_as_float(u & 0xffff0000u);
  return r;
}

// ---------------- combined degree histograms ----------------
// 1024 blocks: bit0 = src/dst, bits1-3 = window, bits4+ = chunk (0..63).
__global__ __launch_bounds__(256) void histboth_kernel(
    const int* __restrict__ src, const int* __restrict__ dst,
    int* __restrict__ degO, int* __restrict__ C) {
  __shared__ int hist[WIN];
  const int isdst = blockIdx.x & 1;
  const int win = (blockIdx.x >> 1) & 7;
  const int chunk = blockIdx.x >> 4;  // 0..63
  const int w0 = win * WIN;
  const int w1 = w0 + WIN;
  const int* __restrict__ arr = isdst ? dst : src;
  for (int i = threadIdx.x; i < WIN; i += 256) hist[i] = 0;
  __syncthreads();
  const int per = NE / NCHUNK;  // 25000
  const int e0 = chunk * per;
  const int e1 = e0 + per;
  for (int e = e0 + threadIdx.x * 4; e + 3 < e1; e += 256 * 4) {
    int4 v = *reinterpret_cast<const int4*>(arr + e);
    if (v.x >= w0 && v.x < w1) atomicAdd(&hist[v.x - w0], 1);
    if (v.y >= w0 && v.y < w1) atomicAdd(&hist[v.y - w0], 1);
    if (v.z >= w0 && v.z < w1) atomicAdd(&hist[v.z - w0], 1);
    if (v.w >= w0 && v.w < w1) atomicAdd(&hist[v.w - w0], 1);
  }
  __syncthreads();
  if (isdst) {
    for (int i = threadIdx.x; i < WIN; i += 256)
      C[(size_t)chunk * NN + w0 + i] = hist[i];
  } else {
    for (int i = threadIdx.x; i < WIN; i += 256) {
      int c = hist[i];
      if (c) atomicAdd(&degO[w0 + i], c);
    }
  }
}

// ---------------- chunk-scan + true degI + padded deg + fused norms ----------------
__global__ __launch_bounds__(256) void chunkscan_kernel(
    int* __restrict__ C, const int* __restrict__ degO,
    int* __restrict__ degI, int* __restrict__ dpad,
    float* __restrict__ ns, float* __restrict__ nd) {
  int n = blockIdx.x * blockDim.x + threadIdx.x;
  if (n >= NN) return;
  int acc = 0;
#pragma unroll
  for (int c = 0; c < NCHUNK; ++c) {
    int t = C[(size_t)c * NN + n];
    C[(size_t)c * NN + n] = acc;
    acc += t;
  }
  degI[n] = acc;
  dpad[n] = (acc + 7) & ~7;
  nd[n] = rsqrtf(fmaxf((float)acc, 1.0f));
  ns[n] = rsqrtf(fmaxf((float)degO[n], 1.0f));
  if (n == 0) dpad[NN] = 0;
}

// ---------------- prefix scan (over NN+1 entries of dpad) ----------------
__global__ __launch_bounds__(1024) void scan1_kernel(
    const int* __restrict__ deg, int* __restrict__ excl,
    int* __restrict__ blk, int n) {
  __shared__ int lds[1024];
  const int tid = threadIdx.x;
  const int gid = blockIdx.x * 1024 + tid;
  int v = (gid < n) ? deg[gid] : 0;
  lds[tid] = v;
  __syncthreads();
  for (int off = 1; off < 1024; off <<= 1) {
    int t = (tid >= off) ? lds[tid - off] : 0;
    __syncthreads();
    lds[tid] += t;
    __syncthreads();
  }
  if (gid < n) excl[gid] = lds[tid] - v;
  if (tid == 1023) blk[blockIdx.x] = lds[1023];
}

__global__ __launch_bounds__(128) void scan2_kernel(int* __restrict__ blk, int nblk) {
  __shared__ int lds[128];
  const int tid = threadIdx.x;
  int v = (tid < nblk) ? blk[tid] : 0;
  lds[tid] = v;
  __syncthreads();
  for (int off = 1; off < 128; off <<= 1) {
    int t = (tid >= off) ? lds[tid - off] : 0;
    __syncthreads();
    lds[tid] += t;
    __syncthreads();
  }
  if (tid < nblk) blk[tid] = lds[tid] - v;
}

__global__ __launch_bounds__(1024) void scan3_kernel(
    int* __restrict__ row_off, const int* __restrict__ blk, int n) {
  int gid = blockIdx.x * 1024 + threadIdx.x;
  if (gid < n) row_off[gid] += blk[gid >> 10];
}

// ---------------- scatter via LDS cursors + fused pad fill ----------------
// 512 blocks = 8 windows x 64 chunks; cursor = row_off + C[chunk] (exclusive).
__global__ __launch_bounds__(256) void scatter2_kernel(
    const int* __restrict__ src, const int* __restrict__ dst,
    const int* __restrict__ row_off, const int* __restrict__ degI,
    const int* __restrict__ C, int* __restrict__ col) {
  __shared__ int cur[WIN];
  const int win = blockIdx.x & 7;
  const int chunk = blockIdx.x >> 3;  // 0..63
  const int w0 = win * WIN;
  const int w1 = w0 + WIN;
  for (int i = threadIdx.x; i < WIN; i += 256)
    cur[i] = row_off[w0 + i] + C[(size_t)chunk * NN + w0 + i];
  __syncthreads();
  const int per = NE / NCHUNK;
  const int e0 = chunk * per;
  const int e1 = e0 + per;
  for (int e = e0 + threadIdx.x * 4; e + 3 < e1; e += 256 * 4) {
    int4 d4 = *reinterpret_cast<const int4*>(dst + e);
    int4 s4 = *reinterpret_cast<const int4*>(src + e);
    if (d4.x >= w0 && d4.x < w1) col[atomicAdd(&cur[d4.x - w0], 1)] = s4.x;
    if (d4.y >= w0 && d4.y < w1) col[atomicAdd(&cur[d4.y - w0], 1)] = s4.y;
    if (d4.z >= w0 && d4.z < w1) col[atomicAdd(&cur[d4.z - w0], 1)] = s4.z;
    if (d4.w >= w0 && d4.w < w1) col[atomicAdd(&cur[d4.w - w0], 1)] = s4.w;
  }
  if (chunk == 0) {
    for (int n = w0 + threadIdx.x; n < w1; n += 256) {
      int e = row_off[n] + degI[n];
      int ee = row_off[n + 1];
      for (; e < ee; ++e) col[e] = NN;
    }
  }
}

// ---------------- all weights transpose+convert in one launch ----------------
__global__ __launch_bounds__(256) void wconv_all_kernel(
    const float* __restrict__ W1, unsigned short* __restrict__ Wt1,
    const float* __restrict__ W2, unsigned short* __restrict__ Wt2,
    const float* __restrict__ W3, unsigned short* __restrict__ Wt3,
    const float* __restrict__ W4, unsigned short* __restrict__ Wt4) {
  int gid = blockIdx.x * blockDim.x + threadIdx.x;
  const float* W;
  unsigned short* Wt;
  int K, C, i;
  if (gid < 16384) { W = W1; Wt = Wt1; K = 128; C = 128; i = gid; }
  else if (gid < 32768) { W = W2; Wt = Wt2; K = 128; C = 128; i = gid - 16384; }
  else if (gid < 65536) { W = W3; Wt = Wt3; K = 128; C = 256; i = gid - 32768; }
  else if (gid < 81920) { W = W4; Wt = Wt4; K = 256; C = 64; i = gid - 65536; }
  else return;
  int c = i % C, k = i / C;
  Wt[(size_t)c * K + k] = f2bf(W[i]);
}

// ---------------- prescale: out = bf16(feat * ns[row]); row NN zeroed --------
__global__ __launch_bounds__(256) void prescale_kernel(
    const float* __restrict__ feat, const float* __restrict__ ns,
    unsigned short* __restrict__ out) {
  int idx = blockIdx.x * blockDim.x + threadIdx.x;
  if (idx >= (NN + 1) * 16) return;
  int row = idx >> 4;
  int c8 = (idx & 15) * 8;
  if (row == NN) {
    uint4 z = {0u, 0u, 0u, 0u};
    *reinterpret_cast<uint4*>(out + (size_t)row * 128 + c8) = z;
    return;
  }
  float sc = ns[row];
  float4 v0 = *reinterpret_cast<const float4*>(feat + (size_t)row * 128 + c8);
  float4 v1 = *reinterpret_cast<const float4*>(feat + (size_t)row * 128 + c8 + 4);
  union { unsigned short u[8]; uint4 v; } p;
  p.u[0] = f2bf(v0.x * sc); p.u[1] = f2bf(v0.y * sc);
  p.u[2] = f2bf(v0.z * sc); p.u[3] = f2bf(v0.w * sc);
  p.u[4] = f2bf(v1.x * sc); p.u[5] = f2bf(v1.y * sc);
  p.u[6] = f2bf(v1.z * sc); p.u[7] = f2bf(v1.w * sc);
  *reinterpret_cast<uint4*>(out + (size_t)row * 128 + c8) = p.v;
}

// ---------------- CSR gather: out[d] = bf16(nd[d] * sum x[s]) ----------------
__global__ __launch_bounds__(256) void agg_bf16_kernel(
    const unsigned short* __restrict__ x, const int* __restrict__ col,
    const int* __restrict__ row_off, const float* __restrict__ nd,
    unsigned short* __restrict__ out, int nN) {
  const int wid = (blockIdx.x * blockDim.x + threadIdx.x) >> 6;
  const int lane = threadIdx.x & 63;
  if (wid >= nN) return;
  const int beg = row_off[wid];
  const int end = row_off[wid + 1];
  const int g = lane >> 3;
  const int lg = lane & 7;

  f32x2 acc[8];
#pragma unroll
  for (int k = 0; k < 8; ++k) acc[k] = f32x2{0.f, 0.f};

#define ACC8(v0, v1)                                \
  acc[0] += unpk(v0.x); acc[1] += unpk(v0.y);       \
  acc[2] += unpk(v0.z); acc[3] += unpk(v0.w);       \
  acc[4] += unpk(v1.x); acc[5] += unpk(v1.y);       \
  acc[6] += unpk(v1.z); acc[7] += unpk(v1.w);

  for (int i0 = beg; i0 < end; i0 += 64) {
    const int rem = end - i0;
    int myc = (lane < rem) ? col[i0 + lane] : NN;
    const int nb = rem < 64 ? rem : 64;  // multiple of 8
    int j = 0;
    for (; j + 16 <= nb; j += 16) {
      int s0 = __shfl(myc, j + g);
      int s1 = __shfl(myc, j + 8 + g);
      const uint4* p0 = reinterpret_cast<const uint4*>(x + (size_t)s0 * 128 + lg * 16);
      const uint4* p1 = reinterpret_cast<const uint4*>(x + (size_t)s1 * 128 + lg * 16);
      uint4 a0 = p0[0];
      uint4 a1 = p0[1];
      uint4 b0 = p1[0];
      uint4 b1 = p1[1];
      ACC8(a0, a1);
      ACC8(b0, b1);
    }
    if (j < nb) {
      int s0 = __shfl(myc, j + g);
      const uint4* p0 = reinterpret_cast<const uint4*>(x + (size_t)s0 * 128 + lg * 16);
      uint4 a0 = p0[0];
      uint4 a1 = p0[1];
      ACC8(a0, a1);
    }
  }
#undef ACC8

#pragma unroll
  for (int k = 0; k < 8; ++k) {
    acc[k].x += __shfl_xor(acc[k].x, 8);
    acc[k].y += __shfl_xor(acc[k].y, 8);
    acc[k].x += __shfl_xor(acc[k].x, 16);
    acc[k].y += __shfl_xor(acc[k].y, 16);
    acc[k].x += __shfl_xor(acc[k].x, 32);
    acc[k].y += __shfl_xor(acc[k].y, 32);
  }
  if (g == 0) {
    float sc = nd[wid];
    union { unsigned short u[16]; uint4 v[2]; } p;
#pragma unroll
    for (int k = 0; k < 8; ++k) {
      p.u[2 * k] = f2bf(acc[k].x * sc);
      p.u[2 * k + 1] = f2bf(acc[k].y * sc);
    }
    uint4* o = reinterpret_cast<uint4*>(out + (size_t)wid * 128 + lg * 16);
    o[0] = p.v[0];
    o[1] = p.v[1];
  }
}

// ---------------- MFMA GEMM with LDS-staged B ----------------
__global__ __launch_bounds__(256) void gemm_mfma_kernel(
    const unsigned short* __restrict__ A, const unsigned short* __restrict__ Wt,
    const float* __restrict__ bias, const float* __restrict__ postscale,
    unsigned short* __restrict__ C, int nrows) {
  constexpr int K = 128, COLS = 128, TM = 64;
  constexpr int NT = COLS / 16;  // 8
  __shared__ unsigned short a_lds[TM * K];
  __shared__ unsigned short b_lds[COLS * K];
  const int row0 = blockIdx.x * TM;
  const int tid = threadIdx.x;
  const int wave = tid >> 6, lane = tid & 63;

  for (int i = tid; i < TM * K * 2 / 16; i += 256) {
    int byte_lin = i * 16;
    int r = byte_lin >> 8;
    int swz = byte_lin ^ ((r & 7) << 4);
    uint4 v = {0u, 0u, 0u, 0u};
    int gr = row0 + r;
    if (gr < nrows)
      v = *reinterpret_cast<const uint4*>(A + (size_t)gr * K + (byte_lin & 255) / 2);
    *reinterpret_cast<uint4*>((char*)a_lds + swz) = v;
  }
  for (int i = tid; i < COLS * K * 2 / 16; i += 256) {
    int byte_lin = i * 16;
    int r = byte_lin >> 8;
    int swz = byte_lin ^ ((r & 7) << 4);
    *reinterpret_cast<uint4*>((char*)b_lds + swz) =
        *reinterpret_cast<const uint4*>((const char*)Wt + byte_lin);
  }
  __syncthreads();

  const int rrow = wave * 16 + (lane & 15);
  const int kofs = (lane >> 4) * 8;
  f32x4 acc[NT];
#pragma unroll
  for (int nt = 0; nt < NT; ++nt) acc[nt] = f32x4{0.f, 0.f, 0.f, 0.f};

  for (int ks = 0; ks < 4; ++ks) {
    const int k0 = ks * 32;
    int abyte = ((rrow * K + k0 + kofs) * 2) ^ ((rrow & 7) << 4);
    bf16x8 a = *reinterpret_cast<const bf16x8*>((const char*)a_lds + abyte);
#pragma unroll
    for (int nt = 0; nt < NT; ++nt) {
      int c = nt * 16 + (lane & 15);
      int bbyte = ((c * K + k0 + kofs) * 2) ^ ((c & 7) << 4);
      bf16x8 b = *reinterpret_cast<const bf16x8*>((const char*)b_lds + bbyte);
      acc[nt] = __builtin_amdgcn_mfma_f32_16x16x32_bf16(a, b, acc[nt], 0, 0, 0);
    }
  }

  __syncthreads();
#pragma unroll
  for (int nt = 0; nt < NT; ++nt) {
    int c = nt * 16 + (lane & 15);
    float bv = bias[c];
#pragma unroll
    for (int r = 0; r < 4; ++r) {
      int lrow = wave * 16 + (lane >> 4) * 4 + r;
      int grow = row0 + lrow;
      float ps = (postscale != nullptr && grow < nrows) ? postscale[grow] : 1.0f;
      float v = (acc[nt][r] + bv) * ps;
      a_lds[lrow * COLS + c] = f2bf(v);
    }
  }
  __syncthreads();
  for (int i = tid; i < TM * COLS * 2 / 16; i += 256) {
    int byte_lin = i * 16;
    int r = byte_lin / (COLS * 2);
    int gr = row0 + r;
    if (gr < nrows)
      *reinterpret_cast<uint4*>(C + (size_t)gr * COLS + (byte_lin % (COLS * 2)) / 2) =
          *reinterpret_cast<const uint4*>((const char*)a_lds + byte_lin);
  }
}

// ---------------- fused MLP + proj, LDS-staged B (80KB plan) ----------------
__global__ __launch_bounds__(256) void mlp_mfma_kernel(
    const unsigned short* __restrict__ H, const unsigned short* __restrict__ Wt3,
    const float* __restrict__ b3, const unsigned short* __restrict__ Wt4,
    const float* __restrict__ b4, float* __restrict__ Out, int nrows) {
  constexpr int TM = 64;
  __shared__ char smem[81920];
  unsigned short* h_lds = (unsigned short*)smem;
  char* bbuf[2] = {smem + 16384, smem + 32768};
  char* z_base = smem + 49152;
  const int row0 = blockIdx.x * TM;
  const int tid = threadIdx.x;
  const int wave = tid >> 6, lane = tid & 63;
  const int l15 = lane & 15;
  const int kofs = (lane >> 4) * 8;

  for (int i = tid; i < TM * 128 * 2 / 16; i += 256) {
    int byte_lin = i * 16;
    int r = byte_lin >> 8;
    int swz = byte_lin ^ ((r & 7) << 4);
    uint4 v = {0u, 0u, 0u, 0u};
    int gr = row0 + r;
    if (gr < nrows)
      v = *reinterpret_cast<const uint4*>(H + (size_t)gr * 128 + (byte_lin & 255) / 2);
    *reinterpret_cast<uint4*>((char*)h_lds + swz) = v;
  }

  auto stage_b3 = [&](int ks, char* dstb) {
#pragma unroll
    for (int it = 0; it < 4; ++it) {
      int byte_lin = (tid + it * 256) * 16;
      int r = byte_lin >> 6;
      int kb = byte_lin & 63;
      int swz = byte_lin ^ (((r >> 1) & 3) << 4);
      *reinterpret_cast<uint4*>(dstb + swz) =
          *reinterpret_cast<const uint4*>((const char*)Wt3 + r * 256 + ks * 64 + kb);
    }
  };
  stage_b3(0, bbuf[0]);
  __syncthreads();

  const int rrow = wave * 16 + l15;
  {
    f32x4 acc[16];
#pragma unroll
    for (int nt = 0; nt < 16; ++nt) acc[nt] = f32x4{0.f, 0.f, 0.f, 0.f};
    for (int ks = 0; ks < 4; ++ks) {
      if (ks < 3) stage_b3(ks + 1, bbuf[(ks + 1) & 1]);
      const char* bl = bbuf[ks & 1];
      int abyte = ((rrow * 128 + ks * 32 + kofs) * 2) ^ ((rrow & 7) << 4);
      bf16x8 a = *reinterpret_cast<const bf16x8*>((const char*)h_lds + abyte);
#pragma unroll
      for (int nt = 0; nt < 16; ++nt) {
        int c = nt * 16 + l15;
        int bbyte = (c * 64 + (kofs / 8) * 16) ^ (((c >> 1) & 3) << 4);
        bf16x8 b = *reinterpret_cast<const bf16x8*>(bl + bbyte);
        acc[nt] = __builtin_amdgcn_mfma_f32_16x16x32_bf16(a, b, acc[nt], 0, 0, 0);
      }
      __syncthreads();
    }
#pragma unroll
    for (int nt = 0; nt < 16; ++nt) {
      int c = nt * 16 + l15;
      float bv = b3[c];
#pragma unroll
      for (int r = 0; r < 4; ++r) {
        int lrow = wave * 16 + (lane >> 4) * 4 + r;
        float v = fmaxf(acc[nt][r] + bv, 0.0f);
        int zb = (lrow * 512 + c * 2) ^ ((lrow & 7) << 4);
        *reinterpret_cast<unsigned short*>(z_base + zb) = f2bf(v);
      }
    }
  }
  __syncthreads();

  char* w4 = smem;
  for (int it = 0; it < 8; ++it) {
    int byte_lin = (tid + it * 256) * 16;
    int r = byte_lin >> 9;
    int swz = byte_lin ^ ((r & 7) << 4);
    *reinterpret_cast<uint4*>(w4 + swz) =
        *reinterpret_cast<const uint4*>((const char*)Wt4 + byte_lin);
  }
  __syncthreads();

  f32x4 acc2[4];
#pragma unroll
  for (int nt = 0; nt < 4; ++nt) acc2[nt] = f32x4{0.f, 0.f, 0.f, 0.f};
  for (int ks = 0; ks < 8; ++ks) {
    const int k0 = ks * 32;
    int zbyte = ((rrow * 256 + k0 + kofs) * 2) ^ ((rrow & 7) << 4);
    bf16x8 a = *reinterpret_cast<const bf16x8*>(z_base + zbyte);
#pragma unroll
    for (int nt = 0; nt < 4; ++nt) {
      int c = nt * 16 + l15;
      int wbyte = (c * 512 + (k0 + kofs) * 2) ^ ((c & 7) << 4);
      bf16x8 b = *reinterpret_cast<const bf16x8*>(w4 + wbyte);
      acc2[nt] = __builtin_amdgcn_mfma_f32_16x16x32_bf16(a, b, acc2[nt], 0, 0, 0);
    }
  }
#pragma unroll
  for (int nt = 0; nt < 4; ++nt) {
    float bv = b4[nt * 16 + l15];
#pragma unroll
    for (int r = 0; r < 4; ++r) acc2[nt][r] += bv;
  }

  float rinv[4];
#pragma unroll
  for (int r = 0; r < 4; ++r) {
    float ss = 0.0f;
#pragma unroll
    for (int nt = 0; nt < 4; ++nt) ss = fmaf(acc2[nt][r], acc2[nt][r], ss);
    ss += __shfl_xor(ss, 1);
    ss += __shfl_xor(ss, 2);
    ss += __shfl_xor(ss, 4);
    ss += __shfl_xor(ss, 8);
    rinv[r] = rsqrtf(ss);
  }
#pragma unroll
  for (int nt = 0; nt < 4; ++nt) {
    int c = nt * 16 + l15;
#pragma unroll
    for (int r = 0; r < 4; ++r) {
      int grow = row0 + wave * 16 + (lane >> 4) * 4 + r;
      if (grow < nrows)
        Out[(size_t)grow * 64 + c] = fmaxf(1e-6f, fabsf(acc2[nt][r]) * rinv[r]);
    }
  }
}

extern "C" void kernel_launch(void* const* d_in, const int* in_sizes, int n_in,
                              void* d_out, int out_size, void* d_ws, size_t ws_size,
                              hipStream_t stream) {
  const float* feat = (const float*)d_in[0];
  const int* src = (const int*)d_in[1];
  const int* dst = (const int*)d_in[2];
  const float* W1 = (const float*)d_in[3];
  const float* b1 = (const float*)d_in[4];
  const float* W2 = (const float*)d_in[5];
  const float* b2 = (const float*)d_in[6];
  const float* W3 = (const float*)d_in[7];
  const float* b3 = (const float*)d_in[8];
  const float* W4 = (const float*)d_in[9];
  const float* b4 = (const float*)d_in[10];
  float* out = (float*)d_out;

  char* ws = (char*)d_ws;
  size_t off = 0;
  auto alloc = [&](size_t bytes) {
    size_t p = off;
    off = (off + bytes + 255) & ~(size_t)255;
    return p;
  };
  float* ns = (float*)(ws + alloc((size_t)NN * 4));
  float* nd = (float*)(ws + alloc((size_t)NN * 4));
  int* row_off = (int*)(ws + alloc((size_t)(NN + 64) * 4));
  int* col = (int*)(ws + alloc((size_t)(NE + 8 * NN + 64) * 4));  // padded CSR
  unsigned short* Wt1 = (unsigned short*)(ws + alloc((size_t)128 * 128 * 2));
  unsigned short* Wt2 = (unsigned short*)(ws + alloc((size_t)128 * 128 * 2));
  unsigned short* Wt3 = (unsigned short*)(ws + alloc((size_t)256 * 128 * 2));
  unsigned short* Wt4 = (unsigned short*)(ws + alloc((size_t)64 * 256 * 2));
  unsigned short* B0 = (unsigned short*)(ws + alloc((size_t)(NN + 1) * 128 * 2));
  unsigned short* B1 = (unsigned short*)(ws + alloc((size_t)(NN + 1) * 128 * 2));

  // CSR build temps: in B0 (dead until prescale) and B1 (dead until agg1)
  int* degO = (int*)B0;
  int* degI = degO + NN;
  int* blk = degI + NN;        // 128 ints
  int* dpad = blk + 128;       // NN+1 ints
  int* C = (int*)B1;           // [64][NN] = 25.6MB (fits B1's 25.60MB)

  hipMemsetAsync(degO, 0, (size_t)NN * 4, stream);

  histboth_kernel<<<1024, 256, 0, stream>>>(src, dst, degO, C);
  chunkscan_kernel<<<(NN + 255) / 256, 256, 0, stream>>>(C, degO, degI, dpad, ns, nd);
  const int nblk = (NN + 1 + 1023) / 1024;  // 99
  scan1_kernel<<<nblk, 1024, 0, stream>>>(dpad, row_off, blk, NN + 1);
  scan2_kernel<<<1, 128, 0, stream>>>(blk, nblk);
  scan3_kernel<<<nblk, 1024, 0, stream>>>(row_off, blk, NN + 1);
  scatter2_kernel<<<512, 256, 0, stream>>>(src, dst, row_off, degI, C, col);

  wconv_all_kernel<<<320, 256, 0, stream>>>(W1, Wt1, W2, Wt2, W3, Wt3, W4, Wt4);

  const int nGemmBlk = (NN + 63) / 64;
  const int aggBlocks = (NN * 64 + 255) / 256;

  prescale_kernel<<<((NN + 1) * 16 + 255) / 256, 256, 0, stream>>>(feat, ns, B0);
  agg_bf16_kernel<<<aggBlocks, 256, 0, stream>>>(B0, col, row_off, nd, B1, NN);
  gemm_mfma_kernel<<<nGemmBlk, 256, 0, stream>>>(B1, Wt1, b1, ns, B0, NN);
  agg_bf16_kernel<<<aggBlocks, 256, 0, stream>>>(B0, col, row_off, nd, B1, NN);
  gemm_mfma_kernel<<<nGemmBlk, 256, 0, stream>>>(B1, Wt2, b2, nullptr, B0, NN);
  mlp_mfma_kernel<<<nGemmBlk, 256, 0, stream>>>(B0, Wt3, b3, Wt4, b4, out, NN);
}